// Round 4
// baseline (629.033 us; speedup 1.0000x reference)
//
#include <hip/hip_runtime.h>

#define BATCH 25
#define LSEQ  11
#define OUTR  4
#define DIM   2048
#define VOCAB 32000
#define KSEL  1024

#define MROWS (BATCH * LSEQ * OUTR)   // 1100
#define MPAD  1152                    // 9 * 128
#define MT 128
#define NT 128
#define BK 32
#define LDT 36                        // LDS tile row stride in halves (+8B pad)

typedef _Float16 half8  __attribute__((ext_vector_type(8)));
typedef _Float16 half4  __attribute__((ext_vector_type(4)));
typedef float    floatx4 __attribute__((ext_vector_type(4)));

// ws layout (halves): [0, VOCAB*MPAD) = Ct (transposed fp16 logits),
//                     [A_OFF, ...)    = A (h as fp16, padded to MPAD rows)
#define LOGITS_ELEMS ((size_t)VOCAB * MPAD)
#define A_OFF        LOGITS_ELEMS
#define WS_BYTES     ((LOGITS_ELEMS + (size_t)MPAD * DIM) * 2)

// ---------------- h fp32 -> fp16 (rows >= 1100 zero-filled) ----------------
__global__ __launch_bounds__(256) void conv_h(const float* __restrict__ h,
                                              _Float16* __restrict__ A) {
    const size_t i = ((size_t)blockIdx.x * 256 + threadIdx.x) * 8;
    const int row = (int)(i >> 11);
    half8 hv = {};
    if (row < MROWS) {
        const floatx4 a = *(const floatx4*)(h + i);
        const floatx4 b = *(const floatx4*)(h + i + 4);
        hv[0] = (_Float16)a[0]; hv[1] = (_Float16)a[1];
        hv[2] = (_Float16)a[2]; hv[3] = (_Float16)a[3];
        hv[4] = (_Float16)b[0]; hv[5] = (_Float16)b[1];
        hv[6] = (_Float16)b[2]; hv[7] = (_Float16)b[3];
    }
    *(half8*)(A + i) = hv;
}

// ---------------- full GEMM: Ct[n, m] = sum_k A[m,k] * W[n,k] ----------------
// grid = (9 m-blocks FAST, 250 n-blocks) so same-W blocks run concurrently.
__global__ __launch_bounds__(256) void gemm_logits(
    const _Float16* __restrict__ A,
    const float*    __restrict__ W,
    _Float16*       __restrict__ Ct)
{
    __shared__ _Float16 As[MT * LDT];
    __shared__ _Float16 Bs[NT * LDT];

    const int m0 = blockIdx.x * MT;
    const int n0 = blockIdx.y * NT;
    const int tid  = threadIdx.x;
    const int wave = tid >> 6, lane = tid & 63;
    const int quad = lane >> 4, l16 = lane & 15;
    const int wm = (wave >> 1) * 64, wn = (wave & 1) * 64;

    const int ar = tid >> 1, ac = (tid & 1) * 16;   // A staging: 2 thr/row
    const int bc = (tid & 7) * 4;                    // B staging: 8 thr/row

    floatx4 acc[4][4];
#pragma unroll
    for (int mt = 0; mt < 4; ++mt)
#pragma unroll
        for (int nt = 0; nt < 4; ++nt) acc[mt][nt] = (floatx4){0.f, 0.f, 0.f, 0.f};

    for (int k0 = 0; k0 < DIM; k0 += BK) {
        __syncthreads();
        // stage A tile: 128 rows x 32 halves
        {
            const _Float16* src = A + (size_t)(m0 + ar) * DIM + k0 + ac;
            *(half8*)(As + ar * LDT + ac)     = *(const half8*)src;
            *(half8*)(As + ar * LDT + ac + 8) = *(const half8*)(src + 8);
        }
        // stage B tile: 128 rows x 32 floats -> fp16
#pragma unroll
        for (int i = 0; i < 4; ++i) {
            const int r = i * 32 + (tid >> 3);
            const floatx4 v = *(const floatx4*)(W + (size_t)(n0 + r) * DIM + k0 + bc);
            half4 hv;
            hv[0] = (_Float16)v[0]; hv[1] = (_Float16)v[1];
            hv[2] = (_Float16)v[2]; hv[3] = (_Float16)v[3];
            *(half4*)(Bs + r * LDT + bc) = hv;
        }
        __syncthreads();

        half8 af[4], bf[4];
#pragma unroll
        for (int t = 0; t < 4; ++t) {
            af[t] = *(const half8*)(As + (wm + t * 16 + l16) * LDT + quad * 8);
            bf[t] = *(const half8*)(Bs + (wn + t * 16 + l16) * LDT + quad * 8);
        }
#pragma unroll
        for (int mt = 0; mt < 4; ++mt)
#pragma unroll
            for (int nt = 0; nt < 4; ++nt)
                acc[mt][nt] = __builtin_amdgcn_mfma_f32_16x16x32_f16(
                    af[mt], bf[nt], acc[mt][nt], 0, 0, 0);
    }

    // epilogue: transposed fp16 store. D layout: col=l16, row=quad*4+reg ->
    // per lane the 4 regs are 4 CONSECUTIVE m at fixed n => one 8-B store.
#pragma unroll
    for (int mt = 0; mt < 4; ++mt)
#pragma unroll
        for (int nt = 0; nt < 4; ++nt) {
            const int m = m0 + wm + mt * 16 + quad * 4;
            const int n = n0 + wn + nt * 16 + l16;
            half4 hv;
            hv[0] = (_Float16)acc[mt][nt][0];
            hv[1] = (_Float16)acc[mt][nt][1];
            hv[2] = (_Float16)acc[mt][nt][2];
            hv[3] = (_Float16)acc[mt][nt][3];
            *(half4*)(Ct + (size_t)n * MPAD + m) = hv;   // m>=1100 junk unused
        }
}

// ---------------- gather: out[bl,o,k] = Ct[idx[bl,k], bl*4+o] ----------------
__global__ __launch_bounds__(256) void gather_logits(
    const _Float16* __restrict__ Ct,
    const int*      __restrict__ index,
    float*          __restrict__ out)
{
    const int gid = blockIdx.x * 256 + threadIdx.x;   // < 281600
    const int bl = gid >> 10, k = gid & 1023;
    const int ridx = index[gid];
    const half4 v = *(const half4*)(Ct + (size_t)ridx * MPAD + bl * 4);
    float* op = out + (size_t)bl * (OUTR * KSEL) + k;
    op[0 * KSEL] = (float)v[0];
    op[1 * KSEL] = (float)v[1];
    op[2 * KSEL] = (float)v[2];
    op[3 * KSEL] = (float)v[3];
}

// ---------------- fallback (fp32 table, R1 kernel) ----------------
#define FKPB 64
#define FKPW 16

__global__ __launch_bounds__(256) void ehead_f32_kernel(
    const float* __restrict__ h,
    const float* __restrict__ wt,
    const int*   __restrict__ index,
    float*       __restrict__ out)
{
    const int nkc = KSEL / FKPB;
    const int bl  = blockIdx.x / nkc;
    const int kc  = blockIdx.x % nkc;
    const int kbase = kc * FKPB;

    __shared__ float hsf[OUTR * DIM];
    const float* hp = h + (size_t)bl * (OUTR * DIM);
    const int tid = threadIdx.x;
#pragma unroll
    for (int i = 0; i < (OUTR * DIM) / (256 * 4); ++i) {
        const int e = (i * 256 + tid) * 4;
        *(float4*)&hsf[e] = *(const float4*)&hp[e];
    }
    __syncthreads();

    const int wave = tid >> 6;
    const int lane = tid & 63;
    const int* ip = index + (size_t)bl * KSEL + kbase + wave * FKPW;
    float*     op = out   + (size_t)bl * (OUTR * KSEL) + kbase + wave * FKPW;

    for (int g = 0; g < FKPW; g += 4) {
        const float4* r0 = (const float4*)(wt + (size_t)ip[g + 0] * DIM);
        const float4* r1 = (const float4*)(wt + (size_t)ip[g + 1] * DIM);
        const float4* r2 = (const float4*)(wt + (size_t)ip[g + 2] * DIM);
        const float4* r3 = (const float4*)(wt + (size_t)ip[g + 3] * DIM);
        float acc[OUTR][4];
#pragma unroll
        for (int o = 0; o < OUTR; ++o)
#pragma unroll
            for (int kk = 0; kk < 4; ++kk) acc[o][kk] = 0.f;
#pragma unroll
        for (int c = 0; c < DIM / 256; ++c) {
            const int off = c * 64 + lane;
            const float4 w0 = r0[off];
            const float4 w1 = r1[off];
            const float4 w2 = r2[off];
            const float4 w3 = r3[off];
#pragma unroll
            for (int o = 0; o < OUTR; ++o) {
                const float4 hv = *(const float4*)&hsf[o * DIM + off * 4];
                acc[o][0] += hv.x * w0.x + hv.y * w0.y + hv.z * w0.z + hv.w * w0.w;
                acc[o][1] += hv.x * w1.x + hv.y * w1.y + hv.z * w1.z + hv.w * w1.w;
                acc[o][2] += hv.x * w2.x + hv.y * w2.y + hv.z * w2.z + hv.w * w2.w;
                acc[o][3] += hv.x * w3.x + hv.y * w3.y + hv.z * w3.z + hv.w * w3.w;
            }
        }
#pragma unroll
        for (int o = 0; o < OUTR; ++o)
#pragma unroll
            for (int kk = 0; kk < 4; ++kk) {
                float v = acc[o][kk];
#pragma unroll
                for (int s = 32; s >= 1; s >>= 1) v += __shfl_xor(v, s, 64);
                acc[o][kk] = v;
            }
        if (lane < 16) {
            float v = 0.f;
#pragma unroll
            for (int oo = 0; oo < OUTR; ++oo)
#pragma unroll
                for (int qq = 0; qq < 4; ++qq)
                    v = (oo * 4 + qq == lane) ? acc[oo][qq] : v;
            op[(lane >> 2) * KSEL + g + (lane & 3)] = v;
        }
    }
}

extern "C" void kernel_launch(void* const* d_in, const int* in_sizes, int n_in,
                              void* d_out, int out_size, void* d_ws, size_t ws_size,
                              hipStream_t stream) {
    const float* h   = (const float*)d_in[0];
    const float* wt  = (const float*)d_in[1];
    const int*   idx = (const int*)d_in[2];
    float*       out = (float*)d_out;

    if (ws_size >= WS_BYTES) {
        _Float16* Ct = (_Float16*)d_ws;
        _Float16* A  = (_Float16*)d_ws + A_OFF;

        conv_h<<<(MPAD * DIM) / (256 * 8), 256, 0, stream>>>(h, A);

        dim3 grid(MPAD / MT, VOCAB / NT);   // (9, 250), m fastest
        gemm_logits<<<grid, 256, 0, stream>>>(A, wt, Ct);

        gather_logits<<<(BATCH * LSEQ * KSEL) / 256, 256, 0, stream>>>(Ct, idx, out);
    } else {
        const int grid = BATCH * LSEQ * (KSEL / FKPB);
        ehead_f32_kernel<<<grid, 256, 0, stream>>>(h, wt, idx, out);
    }
}